// Round 1
// 1251.459 us; speedup vs baseline: 1.0366x; 1.0366x over previous
//
#include <hip/hip_runtime.h>

#define NBUS 118
#define BATCH 4096
#define NN (BATCH * NBUS)          // 483328 nodes
#define END_E (4 * NN)             // 1933312 no-diag edges
#define EF_E (END_E + NN)          // 2416640 full edges
#define NLAYERS 10

#define NBKT 236                   // coarse dst buckets, span 2048: 236*2048 == NN
#define SPAN_SHIFT 11
#define SPAN_MASK 2047
#define TILE 4096                  // edges per binA block
#define ND_TILES (END_E / TILE)    // 472 (exact)
#define F_TILES  (EF_E / TILE)     // 590 (exact)
#define CAP_ND 8960                // avg 8192 per bucket, +8.5 sigma pad
#define CAP_F  11008               // avg 10240 per bucket, +7.6 sigma pad

#define W_ND 8                     // ELL width (slot W-1 doubles as tail descriptor)
#define W_F 9
#define TAILCAP 1048576            // entries per tail array (expected ~40-60K)

// ---------- K1: p, denomInv, cursors, err slots ----------
// (ELL zero-fill removed: binB now writes every slot of every node.)
__global__ void init_kernel(const float* __restrict__ x,
                            const float* __restrict__ ybus,
                            float* __restrict__ p,
                            float* __restrict__ denomInv,
                            int* __restrict__ cursor_nd,
                            int* __restrict__ cursor_f,
                            int* __restrict__ tailCur,
                            float* __restrict__ errOut) {
    int tid = blockIdx.x * blockDim.x + threadIdx.x;
    int stride = gridDim.x * blockDim.x;
    for (int i = tid; i < NN; i += stride) {
        float2 xi = ((const float2*)x)[i];
        p[i] = xi.x - xi.y;
        int b = i / NBUS;
        int j = i - b * NBUS;
        denomInv[i] = 1.0f / (ybus[b * (NBUS * NBUS) + j * (NBUS + 1)] * 100.0f);
    }
    if (tid < 256) {
        cursor_nd[tid] = tid * CAP_ND;
        cursor_f[tid]  = tid * CAP_F;
    }
    if (tid < 2) tailCur[tid] = 0;
    if (tid < NLAYERS + 1) errOut[tid] = 0.0f;
}

// ---------- K2 (binA): tile -> LDS bin by coarse bucket -> chunked staging writes ----------
// staged entry: .x = src | (dstLocal<<19), .y = bits(w*100)
__global__ __launch_bounds__(256) void binA_kernel(
        const int* __restrict__ src_nd, const int* __restrict__ dst_nd,
        const float* __restrict__ ea_nd,
        const int* __restrict__ src_f, const int* __restrict__ dst_f,
        const float* __restrict__ ea_f,
        int* __restrict__ cursor_nd, int* __restrict__ cursor_f,
        uint2* __restrict__ stg_nd, uint2* __restrict__ stg_f) {
    __shared__ uint2 buf[TILE];            // 32 KB
    __shared__ unsigned char sb[TILE];     // 4 KB
    __shared__ int hist[256];
    __shared__ int scanA[256];
    __shared__ int segStart[256];
    __shared__ int segGBase[256];

    bool isF = blockIdx.x >= ND_TILES;
    int tile = isF ? (blockIdx.x - ND_TILES) : blockIdx.x;
    const int* src = isF ? src_f : src_nd;
    const int* dst = isF ? dst_f : dst_nd;
    const float* ea = isF ? ea_f : ea_nd;
    int* cursor = isF ? cursor_f : cursor_nd;
    uint2* stg = isF ? stg_f : stg_nd;
    int cap = isF ? CAP_F : CAP_ND;

    int tid = threadIdx.x;
    int base = tile * TILE;

    hist[tid] = 0;
    __syncthreads();

    #pragma unroll
    for (int k = 0; k < TILE / 256; ++k) {
        int d = dst[base + k * 256 + tid];
        atomicAdd(&hist[d >> SPAN_SHIFT], 1);
    }
    __syncthreads();

    int cnt = hist[tid];
    scanA[tid] = cnt;
    __syncthreads();
    for (int off = 1; off < 256; off <<= 1) {
        int t = (tid >= off) ? scanA[tid - off] : 0;
        __syncthreads();
        scanA[tid] += t;
        __syncthreads();
    }
    int excl = scanA[tid] - cnt;
    segStart[tid] = excl;
    hist[tid] = excl;
    if (tid < NBKT && cnt > 0) segGBase[tid] = atomicAdd(&cursor[tid], cnt);
    __syncthreads();

    #pragma unroll
    for (int k = 0; k < TILE / 256; ++k) {
        int e = base + k * 256 + tid;
        int d = dst[e];
        int bkt = d >> SPAN_SHIFT;
        int pos = atomicAdd(&hist[bkt], 1);
        unsigned dl = (unsigned)(d & SPAN_MASK);
        buf[pos] = make_uint2((unsigned)src[e] | (dl << 19),
                              (unsigned)__float_as_int(ea[e] * 100.0f));
        sb[pos] = (unsigned char)bkt;
    }
    __syncthreads();

    #pragma unroll
    for (int k = 0; k < TILE / 256; ++k) {
        int slot = k * 256 + tid;
        int bkt = sb[slot];
        int gpos = segGBase[bkt] + (slot - segStart[bkt]);
        if (gpos < (bkt + 1) * cap)  // freak-overflow guard
            stg[gpos] = buf[slot];
    }
}

// ---------- K3 (binB): quarter-bucket ELL build fully in LDS, coalesced write-out ----------
// Each block owns a 512-node quarter of one coarse bucket. It scans the whole
// bucket's staged entries (coalesced; bucket data is L2/L3-resident, and the 4
// quarter-blocks of a bucket share blockIdx%8 -> same XCD under round-robin
// dispatch), filters to its quarter, builds the full W-wide ELL slice in LDS
// (zeros included), then writes it out with contiguous int4 stores. This
// replaces the previous random 8B global scatter (161 MB WRITE_SIZE -> ~68 MB)
// and makes init's ELL zero-fill unnecessary.
__global__ __launch_bounds__(512) void binB_kernel(
        const uint2* __restrict__ stg_nd, const uint2* __restrict__ stg_f,
        const int* __restrict__ cursor_nd, const int* __restrict__ cursor_f,
        int2* __restrict__ ellND, int2* __restrict__ ellF,
        int2* __restrict__ tailND, int2* __restrict__ tailF,
        int* __restrict__ tailCur /* [0]=nd [1]=f */) {
    __shared__ int2 slice[512 * W_F];  // 36864 B (nd uses first 512*W_ND)
    __shared__ int h[512];             // per-local-node count
    __shared__ int rk[512];            // per-local-node rank cursor
    __shared__ int tb[512];            // per-local-node tail base (overflow rows only)

    // grid decode: g = (u>>3)*32 + q*8 + (u&7); u = bucket-instance 0..471, q = quarter.
    // => the 4 quarters of a bucket share g%8 (same XCD under round-robin).
    int g = blockIdx.x;
    int q = (g >> 3) & 3;
    int u = ((g >> 5) << 3) | (g & 7);
    bool isF = u >= NBKT;
    int bb = isF ? (u - NBKT) : u;

    const uint2* stg = isF ? stg_f : stg_nd;
    int cap = isF ? CAP_F : CAP_ND;
    int W = isF ? W_F : W_ND;
    int2* ell = isF ? ellF : ellND;
    int2* tail = isF ? tailF : tailND;
    int* tc = isF ? (tailCur + 1) : tailCur;

    int cnt_all = (isF ? cursor_f[bb] : cursor_nd[bb]) - bb * cap;
    if (cnt_all > cap) cnt_all = cap;
    int stgBase = bb * cap;
    int tid = threadIdx.x;

    // zero LDS: slice (only first 512*W needed, zero it exactly), h, rk
    {
        int4* s4 = (int4*)slice;
        int n4 = (512 * W) / 2;  // int4 count
        for (int i = tid; i < n4; i += 512) s4[i] = make_int4(0, 0, 0, 0);
        h[tid] = 0;
        rk[tid] = 0;
    }
    __syncthreads();

    // phase 1: per-node histogram (our quarter only)
    for (int i = tid; i < cnt_all; i += 512) {
        uint2 v = stg[stgBase + i];
        int dl = (v.x >> 19) & SPAN_MASK;
        if ((dl >> 9) == q) atomicAdd(&h[dl & 511], 1);
    }
    __syncthreads();

    // phase 2: tail allocation + descriptor for overflow rows (cnt > W)
    {
        int c = h[tid];
        if (c > W) {
            int len = c - (W - 1);
            int tbase = atomicAdd(tc, len);
            if (tbase + len > TAILCAP) { tbase = 0; len = 0; }  // freak guard
            tb[tid] = tbase;
            slice[(W - 1) * 512 + tid] =
                make_int2((int)(0x80000000u | (unsigned)len), tbase);
        }
    }
    __syncthreads();

    // phase 3: scatter staged -> LDS slice slots / global tail
    for (int i = tid; i < cnt_all; i += 512) {
        uint2 v = stg[stgBase + i];
        int dl = (v.x >> 19) & SPAN_MASK;
        if ((dl >> 9) != q) continue;
        int dl9 = dl & 511;
        int c = h[dl9];
        int r = atomicAdd(&rk[dl9], 1);
        int plain = (c <= W) ? c : (W - 1);
        int2 pr = make_int2((int)(v.x & 0x7FFFF), (int)v.y);
        if (r < plain) slice[r * 512 + dl9] = pr;
        else {
            int pos = tb[dl9] + r - plain;
            if (pos < TAILCAP) tail[pos] = pr;
        }
    }
    __syncthreads();

    // write-out: contiguous int4 stores, 4 KB run per slot-column
    {
        int nodeStart = bb * 2048 + q * 512;
        const int4* s4 = (const int4*)slice;
        int n4 = (512 * W) / 2;
        for (int j = tid; j < n4; j += 512) {
            int idx2 = j * 2;          // int2 index into slice
            int s = idx2 >> 9;         // slot
            int off = idx2 & 511;      // local node (even)
            ((int4*)ell)[(s * NN + nodeStart + off) >> 1] = s4[j];
        }
    }
}

// ---------- K4: layer 0 (theta = 0): out0 = p*denomInv - slack ----------
__global__ void out0_kernel(const float* __restrict__ p,
                            const float* __restrict__ denomInv,
                            float* __restrict__ out) {
    int b = blockIdx.x;
    int j = threadIdx.x;
    int i = b * NBUS + j;
    __shared__ float z0;
    float z = 0.0f;
    if (j < NBUS) z = p[i] * denomInv[i];
    if (j == 0) z0 = z;
    __syncthreads();
    if (j < NBUS) out[i] = z - z0;
}

// ---------- K5: fused layer: ELL gather nd -> out_k ; ELL gather f -> err_{k-1} ----------
template <bool DO_OUT>
__global__ __launch_bounds__(128) void layer_kernel(
        const int2* __restrict__ ellND, const int2* __restrict__ tailND,
        const int2* __restrict__ ellF, const int2* __restrict__ tailF,
        const float* __restrict__ cur,
        const float* __restrict__ p,
        const float* __restrict__ denomInv,
        float* __restrict__ out,
        float* __restrict__ errSlot) {
    int b = blockIdx.x;
    int j = threadIdx.x;
    int i = b * NBUS + j;
    bool act = j < NBUS;
    __shared__ float z0;
    __shared__ float ws2[2];

    float pv = 0.0f, di = 0.0f;
    float sum_nd = 0.0f, sum_f = 0.0f;
    if (act) {
        pv = p[i];
        if (DO_OUT) {
            di = denomInv[i];
            int2 e[W_ND];
            #pragma unroll
            for (int s = 0; s < W_ND - 1; ++s) e[s] = ellND[s * NN + i];
            #pragma unroll
            for (int s = 0; s < W_ND - 1; ++s)
                sum_nd += cur[e[s].x] * __int_as_float(e[s].y);
            int2 last = ellND[(W_ND - 1) * NN + i];
            if (last.x < 0) {  // tail descriptor
                int len = last.x & 0x7FFFFFFF;
                int tbase = last.y;
                for (int t = 0; t < len; ++t) {
                    int2 pr = tailND[tbase + t];
                    sum_nd += cur[pr.x] * __int_as_float(pr.y);
                }
            } else {
                sum_nd += cur[last.x] * __int_as_float(last.y);
            }
        }
        {
            int2 e[W_F];
            #pragma unroll
            for (int s = 0; s < W_F - 1; ++s) e[s] = ellF[s * NN + i];
            #pragma unroll
            for (int s = 0; s < W_F - 1; ++s)
                sum_f += cur[e[s].x] * __int_as_float(e[s].y);
            int2 last = ellF[(W_F - 1) * NN + i];
            if (last.x < 0) {
                int len = last.x & 0x7FFFFFFF;
                int tbase = last.y;
                for (int t = 0; t < len; ++t) {
                    int2 pr = tailF[tbase + t];
                    sum_f += cur[pr.x] * __int_as_float(pr.y);
                }
            } else {
                sum_f += cur[last.x] * __int_as_float(last.y);
            }
        }
    }
    if (DO_OUT) {
        float z = (pv - sum_nd) * di;
        if (j == 0) z0 = z;
        __syncthreads();
        if (act) out[i] = z - z0;
    }
    float acc = act ? fabsf(pv - sum_f) : 0.0f;
    for (int off = 32; off > 0; off >>= 1) acc += __shfl_down(acc, off, 64);
    if ((threadIdx.x & 63) == 0) ws2[threadIdx.x >> 6] = acc;
    __syncthreads();
    if (threadIdx.x == 0) atomicAdd(errSlot, ws2[0] + ws2[1]);
}

extern "C" void kernel_launch(void* const* d_in, const int* in_sizes, int n_in,
                              void* d_out, int out_size, void* d_ws, size_t ws_size,
                              hipStream_t stream) {
    const float* x     = (const float*)d_in[0];
    const int*   ei_nd = (const int*)d_in[2];
    const float* ea_nd = (const float*)d_in[3];
    const int*   ei    = (const int*)d_in[4];
    const float* ea    = (const float*)d_in[5];
    const float* ybus  = (const float*)d_in[6];

    float* out_f = (float*)d_out;
    float* errs  = out_f + NN;

    // workspace carve (4-byte units; keep ELL start 16B-aligned for int4 stores)
    float* wsf       = (float*)d_ws;
    float* p         = wsf;          wsf += NN;
    float* denomInv  = wsf;          wsf += NN;
    float* outA      = wsf;          wsf += NN;
    float* outB      = wsf;          wsf += NN;
    int*   cursor_nd = (int*)wsf;    wsf += 256;
    int*   cursor_f  = (int*)wsf;    wsf += 256;
    int*   tailCur   = (int*)wsf;    wsf += 4;   // keeps 16B alignment (4NN+516 ≡ 0 mod 4)
    int2*  ellND     = (int2*)wsf;   wsf += 2LL * W_ND * NN;
    int2*  ellF      = (int2*)wsf;   wsf += 2LL * W_F * NN;
    int2*  tailND    = (int2*)wsf;   wsf += 2LL * TAILCAP;
    int2*  tailF     = (int2*)wsf;   wsf += 2LL * TAILCAP;
    uint2* stg_nd    = (uint2*)wsf;  wsf += 2LL * NBKT * CAP_ND;
    uint2* stg_f     = (uint2*)wsf;  wsf += 2LL * NBKT * CAP_F;

    const int* src_nd = ei_nd;
    const int* dst_nd = ei_nd + END_E;
    const int* src_f  = ei;
    const int* dst_f  = ei + EF_E;

    // ---- build phase ----
    init_kernel<<<2048, 256, 0, stream>>>(x, ybus, p, denomInv,
                                          cursor_nd, cursor_f, tailCur, errs);
    binA_kernel<<<ND_TILES + F_TILES, 256, 0, stream>>>(
        src_nd, dst_nd, ea_nd, src_f, dst_f, ea,
        cursor_nd, cursor_f, stg_nd, stg_f);
    binB_kernel<<<8 * NBKT, 512, 0, stream>>>(   // 4 quarters x 2 edge-sets x 236 buckets
        stg_nd, stg_f, cursor_nd, cursor_f,
        ellND, ellF, tailND, tailF, tailCur);

    // ---- iterate phase ----
    out0_kernel<<<BATCH, 128, 0, stream>>>(p, denomInv, outA);
    const float* cur = outA;
    for (int k = 1; k <= NLAYERS; ++k) {
        float* nxt = (k == NLAYERS) ? out_f : ((k & 1) ? outB : outA);
        layer_kernel<true><<<BATCH, 128, 0, stream>>>(
            ellND, tailND, ellF, tailF, cur, p, denomInv, nxt, errs + (k - 1));
        cur = nxt;
    }
    layer_kernel<false><<<BATCH, 128, 0, stream>>>(
        ellND, tailND, ellF, tailF, cur, p, denomInv, nullptr, errs + NLAYERS);
}

// Round 2
// 901.430 us; speedup vs baseline: 1.4391x; 1.3883x over previous
//
#include <hip/hip_runtime.h>

#define NBUS 118
#define BATCH 4096
#define NN (BATCH * NBUS)          // 483328 nodes
#define END_E (4 * NN)             // 1933312 no-diag edges
#define EF_E (END_E + NN)          // 2416640 full edges
#define NLAYERS 10

#define NFB 944                    // fine dst buckets, span 512: 944*512 == NN
#define NFBP 1024                  // padded (pow2) for scan
#define FB_SHIFT 9
#define FB_MASK 511
#define TILE 4096                  // edges per binA block
#define ND_TILES (END_E / TILE)    // 472 (exact)
#define F_TILES  (EF_E / TILE)     // 590 (exact)
#define CAP_ND 2432                // mean 2048, +8.5 sigma
#define CAP_F  2944                // mean 2560, +7.6 sigma

#define W_ND 8                     // ELL width (even; slot W-1 doubles as tail descriptor)
#define W_F 10                     // even; desc in slot 9 (padding slot reused)
#define TAILCAP 1048576

#define NERR 64                    // spread error-atomic slots (stride 16 floats = 64B)

typedef int v4i __attribute__((ext_vector_type(4)));
__device__ __forceinline__ v4i ntl4(const v4i* p) { return __builtin_nontemporal_load(p); }

// ---------- K1: p, denomInv, cursors, err partials ----------
__global__ void init_kernel(const float* __restrict__ x,
                            const float* __restrict__ ybus,
                            float* __restrict__ p,
                            float* __restrict__ denomInv,
                            int* __restrict__ cursor_nd,
                            int* __restrict__ cursor_f,
                            int* __restrict__ tailCur,
                            float* __restrict__ errPartial) {
    int tid = blockIdx.x * blockDim.x + threadIdx.x;
    int stride = gridDim.x * blockDim.x;
    for (int i = tid; i < NN; i += stride) {
        float2 xi = ((const float2*)x)[i];
        p[i] = xi.x - xi.y;
        int b = i / NBUS;
        int j = i - b * NBUS;
        denomInv[i] = 1.0f / (ybus[b * (NBUS * NBUS) + j * (NBUS + 1)] * 100.0f);
    }
    for (int i = tid; i < (NLAYERS + 1) * NERR * 16; i += stride) errPartial[i] = 0.0f;
    if (tid < NFBP) {
        cursor_nd[tid] = tid * CAP_ND;
        cursor_f[tid]  = tid * CAP_F;
    }
    if (tid < 2) tailCur[tid] = 0;
}

// ---------- K2 (binA): tile -> LDS bin by FINE bucket -> chunked staging writes ----------
// staged entry: .x = src | (dstLocal9<<19), .y = bits(w*100)
__global__ __launch_bounds__(256) void binA_kernel(
        const int* __restrict__ src_nd, const int* __restrict__ dst_nd,
        const float* __restrict__ ea_nd,
        const int* __restrict__ src_f, const int* __restrict__ dst_f,
        const float* __restrict__ ea_f,
        int* __restrict__ cursor_nd, int* __restrict__ cursor_f,
        uint2* __restrict__ stg_nd, uint2* __restrict__ stg_f) {
    __shared__ uint2 buf[TILE];              // 32 KB
    __shared__ unsigned short sb[TILE];      // 8 KB
    __shared__ int hist[NFBP];               // 4 KB: counts, then write-cursor
    __shared__ int delta[NFBP];              // 4 KB: segGBase - segStart
    __shared__ int tsum[256];                // 1 KB

    bool isF = blockIdx.x >= ND_TILES;
    int tile = isF ? (blockIdx.x - ND_TILES) : blockIdx.x;
    const int* src = isF ? src_f : src_nd;
    const int* dst = isF ? dst_f : dst_nd;
    const float* ea = isF ? ea_f : ea_nd;
    int* cursor = isF ? cursor_f : cursor_nd;
    uint2* stg = isF ? stg_f : stg_nd;
    int cap = isF ? CAP_F : CAP_ND;

    int tid = threadIdx.x;
    int base = tile * TILE;

    #pragma unroll
    for (int k = 0; k < NFBP / 256; ++k) hist[k * 256 + tid] = 0;
    __syncthreads();

    #pragma unroll
    for (int k = 0; k < TILE / 256; ++k) {
        int d = dst[base + k * 256 + tid];
        atomicAdd(&hist[d >> FB_SHIFT], 1);
    }
    __syncthreads();

    // scan over 1024 buckets: each thread owns 4 consecutive
    int c0 = hist[tid * 4 + 0], c1 = hist[tid * 4 + 1];
    int c2 = hist[tid * 4 + 2], c3 = hist[tid * 4 + 3];
    int s = c0 + c1 + c2 + c3;
    tsum[tid] = s;
    __syncthreads();
    for (int off = 1; off < 256; off <<= 1) {
        int t = (tid >= off) ? tsum[tid - off] : 0;
        __syncthreads();
        tsum[tid] += t;
        __syncthreads();
    }
    int basex = tsum[tid] - s;  // exclusive prefix of this thread's 4 buckets
    {
        int st[4];
        st[0] = basex; st[1] = basex + c0; st[2] = st[1] + c1; st[3] = st[2] + c2;
        int cc[4] = {c0, c1, c2, c3};
        #pragma unroll
        for (int k = 0; k < 4; ++k) {
            int bkt = tid * 4 + k;
            hist[bkt] = st[k];                         // becomes write-cursor
            if (bkt < NFB && cc[k] > 0) {
                int gb = atomicAdd(&cursor[bkt], cc[k]);
                delta[bkt] = gb - st[k];               // gpos = delta + slot
            }
        }
    }
    __syncthreads();

    #pragma unroll
    for (int k = 0; k < TILE / 256; ++k) {
        int e = base + k * 256 + tid;
        int d = dst[e];
        int bkt = d >> FB_SHIFT;
        int pos = atomicAdd(&hist[bkt], 1);
        unsigned dl = (unsigned)(d & FB_MASK);
        buf[pos] = make_uint2((unsigned)src[e] | (dl << 19),
                              (unsigned)__float_as_int(ea[e] * 100.0f));
        sb[pos] = (unsigned short)bkt;
    }
    __syncthreads();

    #pragma unroll
    for (int k = 0; k < TILE / 256; ++k) {
        int slot = k * 256 + tid;
        int bkt = sb[slot];
        int gpos = delta[bkt] + slot;
        if (gpos < (bkt + 1) * cap)  // freak-overflow guard
            stg[gpos] = buf[slot];
    }
}

// ---------- K3 (binB): per-fine-bucket ELL build in LDS, pair-packed int4 write-out ----------
__global__ __launch_bounds__(512) void binB_kernel(
        const uint2* __restrict__ stg_nd, const uint2* __restrict__ stg_f,
        const int* __restrict__ cursor_nd, const int* __restrict__ cursor_f,
        int2* __restrict__ ellND, int2* __restrict__ ellF,
        int2* __restrict__ tailND, int2* __restrict__ tailF,
        int* __restrict__ tailCur /* [0]=nd [1]=f */) {
    __shared__ int2 slice[512 * W_F];  // 40960 B (nd uses first 512*W_ND)
    __shared__ int h[512];
    __shared__ int rk[512];
    __shared__ int tb[512];

    int g = blockIdx.x;
    bool isF = g >= NFB;
    int fb = isF ? (g - NFB) : g;

    const uint2* stg = isF ? stg_f : stg_nd;
    int cap = isF ? CAP_F : CAP_ND;
    int W = isF ? W_F : W_ND;
    int2* ell = isF ? ellF : ellND;
    int2* tail = isF ? tailF : tailND;
    int* tc = isF ? (tailCur + 1) : tailCur;

    int cnt_all = (isF ? cursor_f[fb] : cursor_nd[fb]) - fb * cap;
    if (cnt_all > cap) cnt_all = cap;
    int stgBase = fb * cap;
    int tid = threadIdx.x;

    {
        int4* s4 = (int4*)slice;
        int n4 = (512 * W) / 2;
        for (int i = tid; i < n4; i += 512) s4[i] = make_int4(0, 0, 0, 0);
        h[tid] = 0;
        rk[tid] = 0;
    }
    __syncthreads();

    // phase 1: per-node histogram (all entries belong to this block now)
    for (int i = tid; i < cnt_all; i += 512) {
        uint2 v = stg[stgBase + i];
        atomicAdd(&h[(v.x >> 19) & FB_MASK], 1);
    }
    __syncthreads();

    // phase 2: tail allocation + descriptor for overflow rows (cnt > W)
    {
        int c = h[tid];
        if (c > W) {
            int len = c - (W - 1);
            int tbase = atomicAdd(tc, len);
            if (tbase + len > TAILCAP) { tbase = 0; len = 0; }  // freak guard
            tb[tid] = tbase;
            slice[(W - 1) * 512 + tid] =
                make_int2((int)(0x80000000u | (unsigned)len), tbase);
        }
    }
    __syncthreads();

    // phase 3: scatter staged -> LDS slice slots / global tail
    for (int i = tid; i < cnt_all; i += 512) {
        uint2 v = stg[stgBase + i];
        int dl = (v.x >> 19) & FB_MASK;
        int c = h[dl];
        int r = atomicAdd(&rk[dl], 1);
        int plain = (c <= W) ? c : (W - 1);
        int2 pr = make_int2((int)(v.x & 0x7FFFF), (int)v.y);
        if (r < plain) slice[r * 512 + dl] = pr;
        else {
            int pos = tb[dl] + r - plain;
            if (pos < TAILCAP) tail[pos] = pr;
        }
    }
    __syncthreads();

    // write-out: pair-packed int4 planes, nontemporal (don't pollute L2)
    {
        int nodeStart = fb * 512;
        v4i* ell4 = (v4i*)ell;
        int pairs = W >> 1;
        for (int idx = tid; idx < 512 * pairs; idx += 512) {
            int pp = idx >> 9;
            int off = idx & 511;
            int2 a  = slice[(2 * pp) * 512 + off];
            int2 b2 = slice[(2 * pp + 1) * 512 + off];
            v4i val; val.x = a.x; val.y = a.y; val.z = b2.x; val.w = b2.y;
            __builtin_nontemporal_store(val, ell4 + (long)pp * NN + nodeStart + off);
        }
    }
}

// ---------- K4: layer 0 (theta = 0): out0 = p*denomInv - slack ----------
__global__ void out0_kernel(const float* __restrict__ p,
                            const float* __restrict__ denomInv,
                            float* __restrict__ out) {
    int b = blockIdx.x;
    int j = threadIdx.x;
    int i = b * NBUS + j;
    __shared__ float z0;
    float z = 0.0f;
    if (j < NBUS) z = p[i] * denomInv[i];
    if (j == 0) z0 = z;
    __syncthreads();
    if (j < NBUS) out[i] = z - z0;
}

__device__ __forceinline__ float wf(int bits) { return __int_as_float(bits); }

__device__ __forceinline__ float tail_sum(const int2* __restrict__ tail, int tbase, int len,
                                          const float* __restrict__ cur) {
    float s = 0.0f;
    int t = 0;
    for (; t + 2 <= len; t += 2) {
        int2 a = tail[tbase + t];
        int2 b = tail[tbase + t + 1];
        s += cur[a.x] * wf(a.y) + cur[b.x] * wf(b.y);
    }
    if (t < len) {
        int2 a = tail[tbase + t];
        s += cur[a.x] * wf(a.y);
    }
    return s;
}

// ---------- K5: fused layer: ELL gather nd -> out_k ; ELL gather f -> err partials ----------
// 256 threads = 2 batches per block. ELL loads are nontemporal so cur stays L2-resident.
template <bool DO_OUT>
__global__ __launch_bounds__(256) void layer_kernel(
        const int2* __restrict__ ellND, const int2* __restrict__ tailND,
        const int2* __restrict__ ellF, const int2* __restrict__ tailF,
        const float* __restrict__ cur,
        const float* __restrict__ p,
        const float* __restrict__ denomInv,
        float* __restrict__ out,
        float* __restrict__ errPart /* NERR slots, stride 16 */) {
    int tid = threadIdx.x;
    int sub = tid >> 7;
    int j = tid & 127;
    int b = (blockIdx.x << 1) | sub;
    int i = b * NBUS + j;
    bool act = j < NBUS;
    __shared__ float z0s[2];
    __shared__ float ws[4];

    float pv = 0.0f, dv = 0.0f;
    float sum_nd = 0.0f, sum_f = 0.0f;
    if (act) {
        pv = __builtin_nontemporal_load(&p[i]);
        // ---- F edges (err) : 5 pair-planes, slots 0-8 plain, slot 9 = descriptor ----
        {
            const v4i* eF = (const v4i*)ellF;
            v4i r0 = ntl4(eF + 0L * NN + i);
            v4i r1 = ntl4(eF + 1L * NN + i);
            v4i r2 = ntl4(eF + 2L * NN + i);
            v4i r3 = ntl4(eF + 3L * NN + i);
            v4i r4 = ntl4(eF + 4L * NN + i);
            sum_f += cur[r0.x] * wf(r0.y) + cur[r0.z] * wf(r0.w);
            sum_f += cur[r1.x] * wf(r1.y) + cur[r1.z] * wf(r1.w);
            sum_f += cur[r2.x] * wf(r2.y) + cur[r2.z] * wf(r2.w);
            sum_f += cur[r3.x] * wf(r3.y) + cur[r3.z] * wf(r3.w);
            sum_f += cur[r4.x] * wf(r4.y);
            if (r4.z < 0) sum_f += tail_sum(tailF, r4.w, r4.z & 0x7FFFFFFF, cur);
            else          sum_f += cur[r4.z] * wf(r4.w);
        }
        if (DO_OUT) {
            dv = __builtin_nontemporal_load(&denomInv[i]);
            // ---- ND edges (out) : 4 pair-planes, slots 0-6 plain, slot 7 = descriptor ----
            const v4i* eN = (const v4i*)ellND;
            v4i q0 = ntl4(eN + 0L * NN + i);
            v4i q1 = ntl4(eN + 1L * NN + i);
            v4i q2 = ntl4(eN + 2L * NN + i);
            v4i q3 = ntl4(eN + 3L * NN + i);
            sum_nd += cur[q0.x] * wf(q0.y) + cur[q0.z] * wf(q0.w);
            sum_nd += cur[q1.x] * wf(q1.y) + cur[q1.z] * wf(q1.w);
            sum_nd += cur[q2.x] * wf(q2.y) + cur[q2.z] * wf(q2.w);
            sum_nd += cur[q3.x] * wf(q3.y);
            if (q3.z < 0) sum_nd += tail_sum(tailND, q3.w, q3.z & 0x7FFFFFFF, cur);
            else          sum_nd += cur[q3.z] * wf(q3.w);
        }
    }
    if (DO_OUT) {
        float z = (pv - sum_nd) * dv;
        if (j == 0) z0s[sub] = z;
        __syncthreads();
        if (act) out[i] = z - z0s[sub];
    }
    float acc = act ? fabsf(pv - sum_f) : 0.0f;
    for (int off = 32; off > 0; off >>= 1) acc += __shfl_down(acc, off, 64);
    if ((tid & 63) == 0) ws[tid >> 6] = acc;
    __syncthreads();
    if (tid == 0)
        atomicAdd(&errPart[(blockIdx.x & (NERR - 1)) * 16], ws[0] + ws[1] + ws[2] + ws[3]);
}

// ---------- K6: reduce err partials -> errs[11] ----------
__global__ void err_reduce_kernel(const float* __restrict__ errPartial,
                                  float* __restrict__ errs) {
    int l = blockIdx.x;
    int t = threadIdx.x;  // 64
    float v = errPartial[l * (NERR * 16) + t * 16];
    for (int off = 32; off > 0; off >>= 1) v += __shfl_down(v, off, 64);
    if (t == 0) errs[l] = v;
}

extern "C" void kernel_launch(void* const* d_in, const int* in_sizes, int n_in,
                              void* d_out, int out_size, void* d_ws, size_t ws_size,
                              hipStream_t stream) {
    const float* x     = (const float*)d_in[0];
    const int*   ei_nd = (const int*)d_in[2];
    const float* ea_nd = (const float*)d_in[3];
    const int*   ei    = (const int*)d_in[4];
    const float* ea    = (const float*)d_in[5];
    const float* ybus  = (const float*)d_in[6];

    float* out_f = (float*)d_out;
    float* errs  = out_f + NN;

    // workspace carve (4-byte units; ELL planes must stay 16B-aligned for int4)
    float* wsf        = (float*)d_ws;
    float* p          = wsf;          wsf += NN;
    float* denomInv   = wsf;          wsf += NN;
    float* outA       = wsf;          wsf += NN;
    float* outB       = wsf;          wsf += NN;
    int*   cursor_nd  = (int*)wsf;    wsf += NFBP;
    int*   cursor_f   = (int*)wsf;    wsf += NFBP;
    int*   tailCur    = (int*)wsf;    wsf += 4;
    float* errPartial = wsf;          wsf += (NLAYERS + 1) * NERR * 16;  // 11264 (16B-multiple)
    int2*  ellND      = (int2*)wsf;   wsf += 2LL * W_ND * NN;
    int2*  ellF       = (int2*)wsf;   wsf += 2LL * W_F * NN;
    int2*  tailND     = (int2*)wsf;   wsf += 2LL * TAILCAP;
    int2*  tailF      = (int2*)wsf;   wsf += 2LL * TAILCAP;
    uint2* stg_nd     = (uint2*)wsf;  wsf += 2LL * NFB * CAP_ND;
    uint2* stg_f      = (uint2*)wsf;  wsf += 2LL * NFB * CAP_F;

    const int* src_nd = ei_nd;
    const int* dst_nd = ei_nd + END_E;
    const int* src_f  = ei;
    const int* dst_f  = ei + EF_E;

    // ---- build phase ----
    init_kernel<<<2048, 256, 0, stream>>>(x, ybus, p, denomInv,
                                          cursor_nd, cursor_f, tailCur, errPartial);
    binA_kernel<<<ND_TILES + F_TILES, 256, 0, stream>>>(
        src_nd, dst_nd, ea_nd, src_f, dst_f, ea,
        cursor_nd, cursor_f, stg_nd, stg_f);
    binB_kernel<<<2 * NFB, 512, 0, stream>>>(
        stg_nd, stg_f, cursor_nd, cursor_f,
        ellND, ellF, tailND, tailF, tailCur);

    // ---- iterate phase ----
    out0_kernel<<<BATCH, 128, 0, stream>>>(p, denomInv, outA);
    const float* cur = outA;
    for (int k = 1; k <= NLAYERS; ++k) {
        float* nxt = (k == NLAYERS) ? out_f : ((k & 1) ? outB : outA);
        layer_kernel<true><<<BATCH / 2, 256, 0, stream>>>(
            ellND, tailND, ellF, tailF, cur, p, denomInv, nxt,
            errPartial + (long)(k - 1) * NERR * 16);
        cur = nxt;
    }
    layer_kernel<false><<<BATCH / 2, 256, 0, stream>>>(
        ellND, tailND, ellF, tailF, cur, p, denomInv, nullptr,
        errPartial + (long)NLAYERS * NERR * 16);
    err_reduce_kernel<<<NLAYERS + 1, 64, 0, stream>>>(errPartial, errs);
}